// Round 16
// baseline (336.198 us; speedup 1.0000x reference)
//
#include <hip/hip_runtime.h>
#include <stdint.h>

typedef unsigned short u16;
typedef __attribute__((ext_vector_type(8))) short short8;
typedef __attribute__((ext_vector_type(4))) float f32x4;
typedef __attribute__((ext_vector_type(4))) float float4v;
typedef __attribute__((ext_vector_type(4))) unsigned short us4;
typedef __attribute__((ext_vector_type(8))) unsigned short us8;

#define TOK   8192      // B*S
#define DIN   1280
#define DHID  2048
#define NEXP  8
#define RCAP  17408     // 16384 pairs + 8*128 worst-case alignment pad
#define MT128 136       // RCAP/128

#define TRBLK1 5120     // W1: 8 experts * (1280/64) * (2048/64)
#define TRBLK2 5120     // W2
#define RTRBLK 1024     // TOK/8 router blocks
#define XBBLK  2048     // TOK/4 x->bf16 blocks
#define G1BLKS 2176     // (2048/128) * 136

__device__ __forceinline__ float bf2f(u16 u) {
  union { unsigned int i; float f; } v; v.i = ((unsigned int)u) << 16; return v.f;
}
__device__ __forceinline__ u16 f2bf(float f) {
  union { float f; unsigned int i; } v; v.f = f;
  unsigned int x = v.i;
  return (u16)((x + 0x7fffu + ((x >> 16) & 1u)) >> 16);
}

__device__ __forceinline__ void gload16(const u16* g, void* lds) {
  __builtin_amdgcn_global_load_lds(
      (const __attribute__((address_space(1))) unsigned int*)g,
      (__attribute__((address_space(3))) unsigned int*)lds, 16, 0, 0);
}

// ---------------- wide-IO 64x64 transpose tile: f32 [RK,CN] -> bf16 [CN,RK] ----------------
__device__ __forceinline__ void tr_tile(u16* ldsT, const float* in, u16* outp,
                                        int RK, int CN, int rb, int cb)
{
  int tid = threadIdx.x, w = tid >> 6, lane = tid & 63;
  {
    const float* src = in + (size_t)(rb + lane) * CN + cb + w * 16;
    u16 val[16];
    #pragma unroll
    for (int k = 0; k < 4; k++) {
      float4v v = *(const float4v*)(src + k * 4);
      #pragma unroll
      for (int j = 0; j < 4; j++) val[k * 4 + j] = f2bf(v[j]);
    }
    #pragma unroll
    for (int j = 0; j < 16; j++)
      ldsT[(w * 16 + j) * 72 + lane] = val[j];   // whole wave -> one column: 2 lanes/bank
  }
  __syncthreads();
  {
    int oc = tid >> 2, rch = (tid & 3) * 16;
    const u16* s = &ldsT[oc * 72 + rch];
    u16* d = outp + (size_t)(cb + oc) * RK + rb + rch;
    *(us8*)(d)     = *(const us8*)(s);
    *(us8*)(d + 8) = *(const us8*)(s + 8);
  }
}

// ---------------- fused: router FIRST; x->bf16 copy + transpose W1 fill the slack ----------------
__global__ __launch_bounds__(256) void routertr_k(
    const float* __restrict__ w1, u16* __restrict__ W1t,
    const float* __restrict__ x, const float* __restrict__ noise,
    const float* __restrict__ wr, const float* __restrict__ br,
    const float* __restrict__ wn, const float* __restrict__ bn,
    int* __restrict__ topk_e, float* __restrict__ topk_g,
    u16* __restrict__ Xbf)
{
  __shared__ u16 ldsT[64 * 72];
  int id = blockIdx.x;
  int w = threadIdx.x >> 6, lane = threadIdx.x & 63;

  if (id >= RTRBLK + XBBLK) {
    int id2 = id - (RTRBLK + XBBLK);
    int e = id2 / 640, r = id2 % 640;
    int rb = (r >> 5) * 64, cb = (r & 31) * 64;    // W1: [1280, 2048]
    tr_tile(ldsT, w1 + (size_t)e * DIN * DHID, W1t + (size_t)e * DIN * DHID,
            DIN, DHID, rb, cb);
    return;
  }
  if (id >= RTRBLK) {
    // x -> bf16, token order (one wave per token)
    int t = (id - RTRBLK) * 4 + w;
    const float4v* xs = (const float4v*)(x + (size_t)t * DIN);
    us4* d0 = (us4*)(Xbf + (size_t)t * DIN);
    #pragma unroll
    for (int i = 0; i < DIN / 4 / 64; i++) {
      int q = i * 64 + lane;
      float4v v = xs[q];
      us4 o;
      #pragma unroll
      for (int j = 0; j < 4; j++) o[j] = f2bf(v[j]);
      d0[q] = o;
    }
    return;
  }

  // ---- router v3: paired-lane coalesced weight loads, no atomics ----
  int t0 = id * 8 + w * 2;
  int h = lane & 1, dl = lane >> 1;
  const float* xA = x + (size_t)t0 * DIN;
  const float* xB = xA + DIN;

  float ra[4], na[4], rb2[4], nb2[4];
  #pragma unroll
  for (int j = 0; j < 4; j++) { ra[j] = 0.f; na[j] = 0.f; rb2[j] = 0.f; nb2[j] = 0.f; }

  #pragma unroll 4
  for (int d0 = 0; d0 < DIN; d0 += 32) {
    int d = d0 + dl;
    float4v wrv = *(const float4v*)(wr + (size_t)d * 8 + h * 4);
    float4v wnv = *(const float4v*)(wn + (size_t)d * 8 + h * 4);
    float xa = xA[d], xb = xB[d];
    #pragma unroll
    for (int j = 0; j < 4; j++) {
      ra[j]  += xa * wrv[j]; na[j]  += xa * wnv[j];
      rb2[j] += xb * wrv[j]; nb2[j] += xb * wnv[j];
    }
  }
  #pragma unroll
  for (int off = 2; off < 64; off <<= 1) {
    #pragma unroll
    for (int j = 0; j < 4; j++) {
      ra[j]  += __shfl_xor(ra[j],  off);
      na[j]  += __shfl_xor(na[j],  off);
      rb2[j] += __shfl_xor(rb2[j], off);
      nb2[j] += __shfl_xor(nb2[j], off);
    }
  }
  float raO[4], naO[4], rbO[4], nbO[4];
  #pragma unroll
  for (int j = 0; j < 4; j++) {
    raO[j] = __shfl_xor(ra[j], 1);
    naO[j] = __shfl_xor(na[j], 1);
    rbO[j] = __shfl_xor(rb2[j], 1);
    nbO[j] = __shfl_xor(nb2[j], 1);
  }
  if (lane == 0) {
    #pragma unroll
    for (int tt = 0; tt < 2; tt++) {
      int t = t0 + tt;
      float noisy[8];
      #pragma unroll
      for (int j = 0; j < 4; j++) {
        float lg0 = (tt ? rb2[j] : ra[j]) + br[j];
        float nl0 = (tt ? nb2[j] : na[j]) + bn[j];
        float lg1 = (tt ? rbO[j] : raO[j]) + br[4 + j];
        float nl1 = (tt ? nbO[j] : naO[j]) + bn[4 + j];
        float sp0 = (nl0 > 0.f) ? nl0 + log1pf(expf(-nl0)) : log1pf(expf(nl0));
        float sp1 = (nl1 > 0.f) ? nl1 + log1pf(expf(-nl1)) : log1pf(expf(nl1));
        noisy[j]     = lg0 + noise[(size_t)t * 8 + j] * sp0;
        noisy[4 + j] = lg1 + noise[(size_t)t * 8 + 4 + j] * sp1;
      }
      int e0 = 0; float v0 = noisy[0];
      #pragma unroll
      for (int e = 1; e < 8; e++) if (noisy[e] > v0) { v0 = noisy[e]; e0 = e; }
      int e1 = -1; float v1 = -1e30f;
      #pragma unroll
      for (int e = 0; e < 8; e++) if (e != e0 && noisy[e] > v1) { v1 = noisy[e]; e1 = e; }
      float g0 = 1.f / (1.f + expf(v1 - v0));
      topk_e[2*t] = e0; topk_e[2*t+1] = e1;
      topk_g[2*t] = g0; topk_g[2*t+1] = 1.f - g0;
    }
  }
}

// ---------------- deterministic scan: offsets, rowmap, tokmap (+pad zero-fill) ----------------
__global__ __launch_bounds__(1024) void scan_k(
    const int* __restrict__ topk_e, int* __restrict__ rowmap,
    int* __restrict__ tokmap, int* __restrict__ aoffs)
{
  __shared__ int cnt[1024][8];
  __shared__ int tot[8];
  __shared__ int base[8];
  int tid = threadIdx.x;
  int ebuf[16];
  #pragma unroll
  for (int j = 0; j < 16; j++) ebuf[j] = topk_e[tid * 16 + j];
  int c0=0,c1=0,c2=0,c3=0,c4=0,c5=0,c6=0,c7=0;
  #pragma unroll
  for (int j = 0; j < 16; j++) {
    int e = ebuf[j];
    c0 += (e==0); c1 += (e==1); c2 += (e==2); c3 += (e==3);
    c4 += (e==4); c5 += (e==5); c6 += (e==6); c7 += (e==7);
  }
  cnt[tid][0]=c0; cnt[tid][1]=c1; cnt[tid][2]=c2; cnt[tid][3]=c3;
  cnt[tid][4]=c4; cnt[tid][5]=c5; cnt[tid][6]=c6; cnt[tid][7]=c7;
  __syncthreads();

  int w = tid >> 6, lane = tid & 63;
  if (w < 8) {
    int e = w;
    int s[16]; int run = 0;
    #pragma unroll
    for (int j = 0; j < 16; j++) { s[j] = run; run += cnt[lane*16+j][e]; }
    int inc = run;
    for (int off = 1; off < 64; off <<= 1) {
      int v = __shfl_up(inc, off);
      if (lane >= off) inc += v;
    }
    int lane_excl = inc - run;
    #pragma unroll
    for (int j = 0; j < 16; j++) cnt[lane*16+j][e] = lane_excl + s[j];
    if (lane == 63) tot[e] = inc;
  }
  __syncthreads();
  if (tid == 0) {
    int a = 0;
    for (int e = 0; e < 8; e++) { base[e] = a; aoffs[e] = a; a += (tot[e] + 127) & ~127; }
    aoffs[8] = a;
  }
  __syncthreads();
  // pad rows -> token 0 (so indirect A-staging never reads poison)
  if (w < 8) {
    int e = w;
    int region = (tot[e] + 127) & ~127;
    for (int r = tot[e] + lane; r < region; r += 64) tokmap[base[e] + r] = 0;
  }
  int o0 = base[0]+cnt[tid][0], o1 = base[1]+cnt[tid][1], o2 = base[2]+cnt[tid][2],
      o3 = base[3]+cnt[tid][3], o4 = base[4]+cnt[tid][4], o5 = base[5]+cnt[tid][5],
      o6 = base[6]+cnt[tid][6], o7 = base[7]+cnt[tid][7];
  #pragma unroll
  for (int j = 0; j < 16; j++) {
    int p = tid * 16 + j;
    int e = ebuf[j];
    int row = o0;
    row = (e==1) ? o1 : row; row = (e==2) ? o2 : row; row = (e==3) ? o3 : row;
    row = (e==4) ? o4 : row; row = (e==5) ? o5 : row; row = (e==6) ? o6 : row;
    row = (e==7) ? o7 : row;
    o0 += (e==0); o1 += (e==1); o2 += (e==2); o3 += (e==3);
    o4 += (e==4); o5 += (e==5); o6 += (e==6); o7 += (e==7);
    rowmap[p] = row;
    tokmap[row] = p >> 1;
  }
}

// ---------------- 128x128 BK=64 4-wave MFMA GEMM body (R10-proven schedule) ----------------
// IND=true: A is token-ordered (Xbf); per-lane source row = tokmap[row0 + srow[q]].
// Epilogue: LDS-bounce C (stage buffers dead) -> 8x ds_read_b128 + 8x 16B stores/thread.
template<bool IND>
__device__ __forceinline__ void gemm128_body(
    u16* sm, const u16* A, const int* tokmap, const u16* Bt,
    const float* bias, u16* Out,
    const int* aoffs, int K, int N, int relu, int bx, int by)
{
  int row0 = by * 128;
  if (row0 >= aoffs[NEXP]) return;
  int e = 0;
  #pragma unroll
  for (int i = 0; i < NEXP; i++) if (row0 >= aoffs[i + 1]) e = i + 1;
  int ncol0 = bx * 128;
  const u16* Ab = IND ? A : A + (size_t)row0 * K;
  const u16* Bb = Bt + ((size_t)e * N + ncol0) * K;

  int tid = threadIdx.x, w = tid >> 6, lane = tid & 63;
  int wr = w >> 1, wc = w & 1;
  int l15 = lane & 15, l4 = lane >> 4;
  int xorv = (l15 & 7) << 3;

  size_t arow[4]; int skc[4]; int srowb[4];
  #pragma unroll
  for (int q = 0; q < 4; q++) {
    int cd = q * 256 + tid;
    int cs = cd ^ ((cd >> 3) & 7);
    int sr = cs >> 3;
    srowb[q] = sr;
    skc[q]  = (cs & 7) * 8;
    arow[q] = IND ? (size_t)tokmap[row0 + sr] : (size_t)sr;
  }
  int ldsw = w * 1024;

  f32x4 acc[4][4];
  #pragma unroll
  for (int m = 0; m < 4; m++)
    #pragma unroll
    for (int n = 0; n < 4; n++) acc[m][n] = (f32x4){0.f, 0.f, 0.f, 0.f};

  short8 a[4][2], b0[2][2], b1[2][2];

#define STAGE_A(T, BUF) do {                                                  \
    char* d_ = (char*)sm + (BUF) * 32768;                                     \
    int ko_ = (T) * 64;                                                       \
    _Pragma("unroll")                                                         \
    for (int q = 0; q < 4; q++)                                               \
      gload16(Ab + arow[q] * K + ko_ + skc[q], d_ + q*4096 + ldsw);           \
  } while (0)
#define STAGE_B(T, BUF) do {                                                  \
    char* d_ = (char*)sm + (BUF) * 32768 + 16384;                             \
    int ko_ = (T) * 64;                                                       \
    _Pragma("unroll")                                                         \
    for (int q = 0; q < 4; q++)                                               \
      gload16(Bb + (size_t)srowb[q] * K + ko_ + skc[q], d_ + q*4096 + ldsw);  \
  } while (0)
#define RD_A() do {                                                           \
    _Pragma("unroll")                                                         \
    for (int m = 0; m < 4; m++)                                               \
      _Pragma("unroll")                                                       \
      for (int ks = 0; ks < 2; ks++) {                                        \
        int r_ = wr*64 + m*16 + l15;                                          \
        a[m][ks] = *(const short8*)&smA[(r_*64 + ks*32 + l4*8) ^ xorv];       \
      }                                                                       \
  } while (0)
#define RD_B(DST, NH) do {                                                    \
    _Pragma("unroll")                                                         \
    for (int n = 0; n < 2; n++)                                               \
      _Pragma("unroll")                                                       \
      for (int ks = 0; ks < 2; ks++) {                                        \
        int r_ = wc*64 + (NH)*32 + n*16 + l15;                                \
        DST[n][ks] = *(const short8*)&smB[(r_*64 + ks*32 + l4*8) ^ xorv];     \
      }                                                                       \
  } while (0)
#define MFMA16(NH, BB) do {                                                   \
    _Pragma("unroll")                                                         \
    for (int m = 0; m < 4; m++)                                               \
      _Pragma("unroll")                                                       \
      for (int n = 0; n < 2; n++)                                             \
        _Pragma("unroll")                                                     \
        for (int ks = 0; ks < 2; ks++)                                        \
          acc[m][(NH)*2+n] = __builtin_amdgcn_mfma_f32_16x16x32_bf16(         \
              a[m][ks], BB[n][ks], acc[m][(NH)*2+n], 0, 0, 0);                \
  } while (0)
#define BAR __builtin_amdgcn_s_barrier()

  int NT = K >> 6;
  STAGE_A(0, 0);
  STAGE_B(0, 0);
  STAGE_A(1, 1);
  STAGE_B(1, 1);
  asm volatile("s_waitcnt vmcnt(8)" ::: "memory");
  BAR;

  for (int t = 0; t < NT; ++t) {
    int buf = t & 1;
    const u16* smA = sm + buf * 16384;
    const u16* smB = smA + 8192;
    RD_A();
    RD_B(b0, 0);
    RD_B(b1, 1);
    asm volatile("s_waitcnt lgkmcnt(0)" ::: "memory");
    BAR;
    if (t + 2 < NT) {
      STAGE_A(t + 2, buf);
      STAGE_B(t + 2, buf);
    }
    __builtin_amdgcn_s_setprio(1);
    MFMA16(0, b0);
    MFMA16(1, b1);
    __builtin_amdgcn_s_setprio(0);
    if (t + 2 < NT) {
      asm volatile("s_waitcnt vmcnt(8)" ::: "memory");
    } else if (t + 1 < NT) {
      asm volatile("s_waitcnt vmcnt(0)" ::: "memory");
    }
    BAR;
  }
#undef STAGE_A
#undef STAGE_B
#undef RD_A
#undef RD_B
#undef MFMA16
#undef BAR

  // ---- epilogue: bounce C through LDS, store 16B-vectorized ----
  {
    u16* ldsC = sm;                       // [128][136] u16 = 34 KB (stage bufs dead)
    #pragma unroll
    for (int in = 0; in < 4; in++) {
      int c = wc * 64 + in * 16 + l15;
      float bv = bias[(size_t)e * N + ncol0 + c];
      #pragma unroll
      for (int im = 0; im < 4; im++) {
        int rb = wr * 64 + im * 16 + l4 * 4;
        #pragma unroll
        for (int j = 0; j < 4; j++) {
          float v = acc[im][in][j] + bv;
          if (relu) v = fmaxf(v, 0.f);
          ldsC[(rb + j) * 136 + c] = f2bf(v);
        }
      }
    }
    asm volatile("s_waitcnt lgkmcnt(0)" ::: "memory");   // own ds_writes drained
    __builtin_amdgcn_s_barrier();
    int row = tid >> 1, half = tid & 1;
    const u16* s = &ldsC[row * 136 + half * 64];
    u16* d = Out + (size_t)(row0 + row) * N + ncol0 + half * 64;
    us8 v0_ = *(const us8*)(s +  0);
    us8 v1_ = *(const us8*)(s +  8);
    us8 v2_ = *(const us8*)(s + 16);
    us8 v3_ = *(const us8*)(s + 24);
    us8 v4_ = *(const us8*)(s + 32);
    us8 v5_ = *(const us8*)(s + 40);
    us8 v6_ = *(const us8*)(s + 48);
    us8 v7_ = *(const us8*)(s + 56);
    *(us8*)(d +  0) = v0_;
    *(us8*)(d +  8) = v1_;
    *(us8*)(d + 16) = v2_;
    *(us8*)(d + 24) = v3_;
    *(us8*)(d + 32) = v4_;
    *(us8*)(d + 40) = v5_;
    *(us8*)(d + 48) = v6_;
    *(us8*)(d + 56) = v7_;
  }
}

// ---------------- GEMM1 (indirect A via tokmap) FIRST; transpose(W2) drains into slack ----------------
__global__ __launch_bounds__(256, 2) void gemm1tr_k(
    const u16* __restrict__ Xbf, const u16* __restrict__ Bt,
    const float* __restrict__ bias, u16* __restrict__ Out,
    const int* __restrict__ aoffs, const int* __restrict__ tokmap,
    const float* __restrict__ w2, u16* __restrict__ W2t)
{
  extern __shared__ u16 sm[];
  int id = blockIdx.x;
  if (id < G1BLKS) {
    int per = G1BLKS >> 3;
    int sid = (id & 7) * per + (id >> 3);           // XCD-chunked swizzle (2176 % 8 == 0)
    gemm128_body<true>(sm, Xbf, tokmap, Bt, bias, Out, aoffs, DIN, DHID, 1,
                       sid % 16, sid / 16);
    return;
  }
  int id2 = id - G1BLKS;
  int e = id2 / 640, r = id2 % 640;
  int rb = (r / 20) * 64, cb = (r % 20) * 64;       // W2: [2048, 1280]
  tr_tile(sm, w2 + (size_t)e * DHID * DIN, W2t + (size_t)e * DHID * DIN,
          DHID, DIN, rb, cb);
}

// ---------------- GEMM2: plain 128x128 ----------------
__global__ __launch_bounds__(256, 2) void gemm128_k(
    const u16* __restrict__ A, const u16* __restrict__ Bt,
    const float* __restrict__ bias, u16* __restrict__ Out,
    const int* __restrict__ aoffs, int K, int N, int relu)
{
  extern __shared__ u16 sm[];
  int nwgx = gridDim.x;
  int id = blockIdx.y * nwgx + blockIdx.x;
  int per = (nwgx * gridDim.y) >> 3;
  int sid = (id & 7) * per + (id >> 3);
  gemm128_body<false>(sm, A, nullptr, Bt, bias, Out, aoffs, K, N, relu,
                      sid % nwgx, sid / nwgx);
}

// ---------------- ln v2: one wave per token, vectorized, shuffle-only reduce ----------------
__global__ __launch_bounds__(256) void ln_k(
    const float* __restrict__ x, const u16* __restrict__ Y,
    const int* __restrict__ rowmap, const int* __restrict__ topk_e,
    const float* __restrict__ topk_g, const float* __restrict__ gamma,
    const float* __restrict__ beta, float* __restrict__ out)
{
  int w = threadIdx.x >> 6, lane = threadIdx.x & 63;
  int t = blockIdx.x * 4 + w;
  int r0 = rowmap[2*t], r1 = rowmap[2*t+1];
  int e0 = topk_e[2*t], e1 = topk_e[2*t+1];
  float g0 = topk_g[2*t], g1 = topk_g[2*t+1];
  const float4v* xt = (const float4v*)(x + (size_t)t * DIN);
  const us4* y0p = (const us4*)(Y + (size_t)r0 * DIN);
  const us4* y1p = (const us4*)(Y + (size_t)r1 * DIN);
  float4v v0[5], v1[5];
  float s0 = 0.f, q0 = 0.f, s1 = 0.f, q1 = 0.f;
  #pragma unroll
  for (int i = 0; i < 5; i++) {
    int q = i * 64 + lane;
    float4v xv = xt[q];
    us4 ya = y0p[q], yb = y1p[q];
    #pragma unroll
    for (int j = 0; j < 4; j++) {
      float aa = xv[j] + bf2f(ya[j]);
      float bb = xv[j] + bf2f(yb[j]);
      v0[i][j] = aa; v1[i][j] = bb;
      s0 += aa; q0 += aa * aa; s1 += bb; q1 += bb * bb;
    }
  }
  #pragma unroll
  for (int off = 32; off; off >>= 1) {
    s0 += __shfl_xor(s0, off); q0 += __shfl_xor(q0, off);
    s1 += __shfl_xor(s1, off); q1 += __shfl_xor(q1, off);
  }
  const float inv = 1.f / DIN;
  float mu0 = s0 * inv, mu1 = s1 * inv;
  float rs0 = rsqrtf(fmaxf(q0 * inv - mu0 * mu0, 0.f) + 1e-6f);
  float rs1 = rsqrtf(fmaxf(q1 * inv - mu1 * mu1, 0.f) + 1e-6f);
  const float4v* ga0 = (const float4v*)(gamma + (size_t)e0 * DIN);
  const float4v* be0 = (const float4v*)(beta  + (size_t)e0 * DIN);
  const float4v* ga1 = (const float4v*)(gamma + (size_t)e1 * DIN);
  const float4v* be1 = (const float4v*)(beta  + (size_t)e1 * DIN);
  float4v* op = (float4v*)(out + (size_t)t * DIN);
  #pragma unroll
  for (int i = 0; i < 5; i++) {
    int q = i * 64 + lane;
    float4v gA = ga0[q], bA = be0[q], gB = ga1[q], bB = be1[q];
    float4v o;
    #pragma unroll
    for (int j = 0; j < 4; j++) {
      float n0 = (v0[i][j] - mu0) * rs0 * gA[j] + bA[j];
      float n1 = (v1[i][j] - mu1) * rs1 * gB[j] + bB[j];
      o[j] = g0 * n0 + g1 * n1;
    }
    op[q] = o;
  }
}

extern "C" void kernel_launch(void* const* d_in, const int* in_sizes, int n_in,
                              void* d_out, int out_size, void* d_ws, size_t ws_size,
                              hipStream_t stream)
{
  const float* x     = (const float*)d_in[0];
  const float* noise = (const float*)d_in[1];
  const float* wr    = (const float*)d_in[2];
  const float* br    = (const float*)d_in[3];
  const float* wn    = (const float*)d_in[4];
  const float* bn    = (const float*)d_in[5];
  const float* w1    = (const float*)d_in[6];
  const float* b1    = (const float*)d_in[7];
  const float* w2    = (const float*)d_in[8];
  const float* b2    = (const float*)d_in[9];
  const float* gamma = (const float*)d_in[10];
  const float* beta  = (const float*)d_in[11];
  float* out = (float*)d_out;
  char* ws = (char*)d_ws;

  int*   aoffs   = (int*)(ws + 128);
  int*   rowmap  = (int*)(ws + 4096);
  int*   topk_e  = (int*)(ws + 4096 + 65536);
  float* topk_g  = (float*)(ws + 4096 + 2 * 65536);
  int*   tokmap  = (int*)(ws + 4096 + 3 * 65536);   // RCAP ints = 68 KB

  const size_t XB_OFF   = (size_t)1 << 20;
  const size_t XB_BYTES = (size_t)TOK * DIN * 2;    // 21.0 MB
  const size_t H_BYTES  = (size_t)RCAP * DHID * 2;  // 71.3 MB
  const size_t Y_BYTES  = (size_t)RCAP * DIN * 2;   // 44.6 MB
  const size_t WT_BYTES = (size_t)NEXP * DHID * DIN * 2; // 41.9 MB each
  u16* Xbf = (u16*)(ws + XB_OFF);
  u16* Hb  = (u16*)(ws + XB_OFF + XB_BYTES);
  u16* Yb  = (u16*)(ws + XB_OFF + XB_BYTES + H_BYTES);
  u16* W1t = (u16*)(ws + XB_OFF + XB_BYTES + H_BYTES + Y_BYTES);
  u16* W2t = (u16*)(ws + XB_OFF + XB_BYTES + H_BYTES + Y_BYTES + WT_BYTES);

  routertr_k<<<RTRBLK + XBBLK + TRBLK1, 256, 0, stream>>>(
      w1, W1t, x, noise, wr, br, wn, bn, topk_e, topk_g, Xbf);
  scan_k<<<1, 1024, 0, stream>>>(topk_e, rowmap, tokmap, aoffs);
  gemm1tr_k<<<G1BLKS + TRBLK2, 256, 65536, stream>>>(Xbf, W1t, b1, Hb, aoffs, tokmap, w2, W2t);
  gemm128_k<<<dim3(DIN/128, MT128), 256, 65536, stream>>>(Hb, W2t, b2, Yb, aoffs, DHID, DIN, 0);
  ln_k<<<TOK/4, 256, 0, stream>>>(x, Yb, rowmap, topk_e, topk_g, gamma, beta, out);
}

// Round 17
// 320.937 us; speedup vs baseline: 1.0476x; 1.0476x over previous
//
#include <hip/hip_runtime.h>
#include <stdint.h>

typedef unsigned short u16;
typedef __attribute__((ext_vector_type(8))) short short8;
typedef __attribute__((ext_vector_type(4))) float f32x4;
typedef __attribute__((ext_vector_type(4))) float float4v;
typedef __attribute__((ext_vector_type(4))) unsigned short us4;
typedef __attribute__((ext_vector_type(8))) unsigned short us8;

#define TOK   8192      // B*S
#define DIN   1280
#define DHID  2048
#define NEXP  8
#define RCAP  17408     // 16384 pairs + 8*128 worst-case alignment pad
#define MT128 136       // RCAP/128

#define TRBLK1 5120     // W1: 8 experts * (1280/64) * (2048/64)
#define TRBLK2 5120     // W2
#define RTRBLK 1024     // TOK/8 router blocks
#define XBBLK  2048     // TOK/4 x->bf16 blocks
#define G1BLKS 2176     // (2048/128) * 136

__device__ __forceinline__ float bf2f(u16 u) {
  union { unsigned int i; float f; } v; v.i = ((unsigned int)u) << 16; return v.f;
}
__device__ __forceinline__ u16 f2bf(float f) {
  union { float f; unsigned int i; } v; v.f = f;
  unsigned int x = v.i;
  return (u16)((x + 0x7fffu + ((x >> 16) & 1u)) >> 16);
}

__device__ __forceinline__ void gload16(const u16* g, void* lds) {
  __builtin_amdgcn_global_load_lds(
      (const __attribute__((address_space(1))) unsigned int*)g,
      (__attribute__((address_space(3))) unsigned int*)lds, 16, 0, 0);
}

// ---------------- wide-IO 64x64 transpose tile: f32 [RK,CN] -> bf16 [CN,RK] ----------------
__device__ __forceinline__ void tr_tile(u16* ldsT, const float* in, u16* outp,
                                        int RK, int CN, int rb, int cb)
{
  int tid = threadIdx.x, w = tid >> 6, lane = tid & 63;
  {
    const float* src = in + (size_t)(rb + lane) * CN + cb + w * 16;
    u16 val[16];
    #pragma unroll
    for (int k = 0; k < 4; k++) {
      float4v v = *(const float4v*)(src + k * 4);
      #pragma unroll
      for (int j = 0; j < 4; j++) val[k * 4 + j] = f2bf(v[j]);
    }
    #pragma unroll
    for (int j = 0; j < 16; j++)
      ldsT[(w * 16 + j) * 72 + lane] = val[j];   // whole wave -> one column: 2 lanes/bank
  }
  __syncthreads();
  {
    int oc = tid >> 2, rch = (tid & 3) * 16;
    const u16* s = &ldsT[oc * 72 + rch];
    u16* d = outp + (size_t)(cb + oc) * RK + rb + rch;
    *(us8*)(d)     = *(const us8*)(s);
    *(us8*)(d + 8) = *(const us8*)(s + 8);
  }
}

// ---------------- fused: router FIRST; x->bf16 copy + transpose W1 fill the slack ----------------
__global__ __launch_bounds__(256) void routertr_k(
    const float* __restrict__ w1, u16* __restrict__ W1t,
    const float* __restrict__ x, const float* __restrict__ noise,
    const float* __restrict__ wr, const float* __restrict__ br,
    const float* __restrict__ wn, const float* __restrict__ bn,
    int* __restrict__ topk_e, float* __restrict__ topk_g,
    u16* __restrict__ Xbf)
{
  __shared__ u16 ldsT[64 * 72];
  int id = blockIdx.x;
  int w = threadIdx.x >> 6, lane = threadIdx.x & 63;

  if (id >= RTRBLK + XBBLK) {
    int id2 = id - (RTRBLK + XBBLK);
    int e = id2 / 640, r = id2 % 640;
    int rb = (r >> 5) * 64, cb = (r & 31) * 64;    // W1: [1280, 2048]
    tr_tile(ldsT, w1 + (size_t)e * DIN * DHID, W1t + (size_t)e * DIN * DHID,
            DIN, DHID, rb, cb);
    return;
  }
  if (id >= RTRBLK) {
    // x -> bf16, token order (one wave per token)
    int t = (id - RTRBLK) * 4 + w;
    const float4v* xs = (const float4v*)(x + (size_t)t * DIN);
    us4* d0 = (us4*)(Xbf + (size_t)t * DIN);
    #pragma unroll
    for (int i = 0; i < DIN / 4 / 64; i++) {
      int q = i * 64 + lane;
      float4v v = xs[q];
      us4 o;
      #pragma unroll
      for (int j = 0; j < 4; j++) o[j] = f2bf(v[j]);
      d0[q] = o;
    }
    return;
  }

  // ---- router v3: paired-lane coalesced weight loads, no atomics ----
  int t0 = id * 8 + w * 2;
  int h = lane & 1, dl = lane >> 1;
  const float* xA = x + (size_t)t0 * DIN;
  const float* xB = xA + DIN;

  float ra[4], na[4], rb2[4], nb2[4];
  #pragma unroll
  for (int j = 0; j < 4; j++) { ra[j] = 0.f; na[j] = 0.f; rb2[j] = 0.f; nb2[j] = 0.f; }

  #pragma unroll 4
  for (int d0 = 0; d0 < DIN; d0 += 32) {
    int d = d0 + dl;
    float4v wrv = *(const float4v*)(wr + (size_t)d * 8 + h * 4);
    float4v wnv = *(const float4v*)(wn + (size_t)d * 8 + h * 4);
    float xa = xA[d], xb = xB[d];
    #pragma unroll
    for (int j = 0; j < 4; j++) {
      ra[j]  += xa * wrv[j]; na[j]  += xa * wnv[j];
      rb2[j] += xb * wrv[j]; nb2[j] += xb * wnv[j];
    }
  }
  #pragma unroll
  for (int off = 2; off < 64; off <<= 1) {
    #pragma unroll
    for (int j = 0; j < 4; j++) {
      ra[j]  += __shfl_xor(ra[j],  off);
      na[j]  += __shfl_xor(na[j],  off);
      rb2[j] += __shfl_xor(rb2[j], off);
      nb2[j] += __shfl_xor(nb2[j], off);
    }
  }
  float raO[4], naO[4], rbO[4], nbO[4];
  #pragma unroll
  for (int j = 0; j < 4; j++) {
    raO[j] = __shfl_xor(ra[j], 1);
    naO[j] = __shfl_xor(na[j], 1);
    rbO[j] = __shfl_xor(rb2[j], 1);
    nbO[j] = __shfl_xor(nb2[j], 1);
  }
  if (lane == 0) {
    #pragma unroll
    for (int tt = 0; tt < 2; tt++) {
      int t = t0 + tt;
      float noisy[8];
      #pragma unroll
      for (int j = 0; j < 4; j++) {
        float lg0 = (tt ? rb2[j] : ra[j]) + br[j];
        float nl0 = (tt ? nb2[j] : na[j]) + bn[j];
        float lg1 = (tt ? rbO[j] : raO[j]) + br[4 + j];
        float nl1 = (tt ? nbO[j] : naO[j]) + bn[4 + j];
        float sp0 = (nl0 > 0.f) ? nl0 + log1pf(expf(-nl0)) : log1pf(expf(nl0));
        float sp1 = (nl1 > 0.f) ? nl1 + log1pf(expf(-nl1)) : log1pf(expf(nl1));
        noisy[j]     = lg0 + noise[(size_t)t * 8 + j] * sp0;
        noisy[4 + j] = lg1 + noise[(size_t)t * 8 + 4 + j] * sp1;
      }
      int e0 = 0; float v0 = noisy[0];
      #pragma unroll
      for (int e = 1; e < 8; e++) if (noisy[e] > v0) { v0 = noisy[e]; e0 = e; }
      int e1 = -1; float v1 = -1e30f;
      #pragma unroll
      for (int e = 0; e < 8; e++) if (e != e0 && noisy[e] > v1) { v1 = noisy[e]; e1 = e; }
      float g0 = 1.f / (1.f + expf(v1 - v0));
      topk_e[2*t] = e0; topk_e[2*t+1] = e1;
      topk_g[2*t] = g0; topk_g[2*t+1] = 1.f - g0;
    }
  }
}

// ---------------- deterministic scan: offsets, rowmap, tokmap (+pad zero-fill) ----------------
__global__ __launch_bounds__(1024) void scan_k(
    const int* __restrict__ topk_e, int* __restrict__ rowmap,
    int* __restrict__ tokmap, int* __restrict__ aoffs)
{
  __shared__ int cnt[1024][8];
  __shared__ int tot[8];
  __shared__ int base[8];
  int tid = threadIdx.x;
  int ebuf[16];
  #pragma unroll
  for (int j = 0; j < 16; j++) ebuf[j] = topk_e[tid * 16 + j];
  int c0=0,c1=0,c2=0,c3=0,c4=0,c5=0,c6=0,c7=0;
  #pragma unroll
  for (int j = 0; j < 16; j++) {
    int e = ebuf[j];
    c0 += (e==0); c1 += (e==1); c2 += (e==2); c3 += (e==3);
    c4 += (e==4); c5 += (e==5); c6 += (e==6); c7 += (e==7);
  }
  cnt[tid][0]=c0; cnt[tid][1]=c1; cnt[tid][2]=c2; cnt[tid][3]=c3;
  cnt[tid][4]=c4; cnt[tid][5]=c5; cnt[tid][6]=c6; cnt[tid][7]=c7;
  __syncthreads();

  int w = tid >> 6, lane = tid & 63;
  if (w < 8) {
    int e = w;
    int s[16]; int run = 0;
    #pragma unroll
    for (int j = 0; j < 16; j++) { s[j] = run; run += cnt[lane*16+j][e]; }
    int inc = run;
    for (int off = 1; off < 64; off <<= 1) {
      int v = __shfl_up(inc, off);
      if (lane >= off) inc += v;
    }
    int lane_excl = inc - run;
    #pragma unroll
    for (int j = 0; j < 16; j++) cnt[lane*16+j][e] = lane_excl + s[j];
    if (lane == 63) tot[e] = inc;
  }
  __syncthreads();
  if (tid == 0) {
    int a = 0;
    for (int e = 0; e < 8; e++) { base[e] = a; aoffs[e] = a; a += (tot[e] + 127) & ~127; }
    aoffs[8] = a;
  }
  __syncthreads();
  // pad rows -> token 0 (so indirect A-staging never reads poison)
  if (w < 8) {
    int e = w;
    int region = (tot[e] + 127) & ~127;
    for (int r = tot[e] + lane; r < region; r += 64) tokmap[base[e] + r] = 0;
  }
  int o0 = base[0]+cnt[tid][0], o1 = base[1]+cnt[tid][1], o2 = base[2]+cnt[tid][2],
      o3 = base[3]+cnt[tid][3], o4 = base[4]+cnt[tid][4], o5 = base[5]+cnt[tid][5],
      o6 = base[6]+cnt[tid][6], o7 = base[7]+cnt[tid][7];
  #pragma unroll
  for (int j = 0; j < 16; j++) {
    int p = tid * 16 + j;
    int e = ebuf[j];
    int row = o0;
    row = (e==1) ? o1 : row; row = (e==2) ? o2 : row; row = (e==3) ? o3 : row;
    row = (e==4) ? o4 : row; row = (e==5) ? o5 : row; row = (e==6) ? o6 : row;
    row = (e==7) ? o7 : row;
    o0 += (e==0); o1 += (e==1); o2 += (e==2); o3 += (e==3);
    o4 += (e==4); o5 += (e==5); o6 += (e==6); o7 += (e==7);
    rowmap[p] = row;
    tokmap[row] = p >> 1;
  }
}

// ---------------- 128x128 BK=64 4-wave MFMA GEMM body (R10-proven schedule) ----------------
// IND=true: A is token-ordered (Xbf); per-lane source row = tokmap[row0 + srow[q]]
// (global_load_lds source addresses are per-lane; LDS dest stays linear).
template<bool IND>
__device__ __forceinline__ void gemm128_body(
    u16* sm, const u16* A, const int* tokmap, const u16* Bt,
    const float* bias, u16* Out,
    const int* aoffs, int K, int N, int relu, int bx, int by)
{
  int row0 = by * 128;
  if (row0 >= aoffs[NEXP]) return;
  int e = 0;
  #pragma unroll
  for (int i = 0; i < NEXP; i++) if (row0 >= aoffs[i + 1]) e = i + 1;
  int ncol0 = bx * 128;
  const u16* Ab = IND ? A : A + (size_t)row0 * K;
  const u16* Bb = Bt + ((size_t)e * N + ncol0) * K;

  int tid = threadIdx.x, w = tid >> 6, lane = tid & 63;
  int wr = w >> 1, wc = w & 1;
  int l15 = lane & 15, l4 = lane >> 4;
  int xorv = (l15 & 7) << 3;

  size_t arow[4]; int skc[4]; int srowb[4];
  #pragma unroll
  for (int q = 0; q < 4; q++) {
    int cd = q * 256 + tid;
    int cs = cd ^ ((cd >> 3) & 7);
    int sr = cs >> 3;
    srowb[q] = sr;
    skc[q]  = (cs & 7) * 8;
    arow[q] = IND ? (size_t)tokmap[row0 + sr] : (size_t)sr;
  }
  int ldsw = w * 1024;

  f32x4 acc[4][4];
  #pragma unroll
  for (int m = 0; m < 4; m++)
    #pragma unroll
    for (int n = 0; n < 4; n++) acc[m][n] = (f32x4){0.f, 0.f, 0.f, 0.f};

  short8 a[4][2], b0[2][2], b1[2][2];

#define STAGE_A(T, BUF) do {                                                  \
    char* d_ = (char*)sm + (BUF) * 32768;                                     \
    int ko_ = (T) * 64;                                                       \
    _Pragma("unroll")                                                         \
    for (int q = 0; q < 4; q++)                                               \
      gload16(Ab + arow[q] * K + ko_ + skc[q], d_ + q*4096 + ldsw);           \
  } while (0)
#define STAGE_B(T, BUF) do {                                                  \
    char* d_ = (char*)sm + (BUF) * 32768 + 16384;                             \
    int ko_ = (T) * 64;                                                       \
    _Pragma("unroll")                                                         \
    for (int q = 0; q < 4; q++)                                               \
      gload16(Bb + (size_t)srowb[q] * K + ko_ + skc[q], d_ + q*4096 + ldsw);  \
  } while (0)
#define RD_A() do {                                                           \
    _Pragma("unroll")                                                         \
    for (int m = 0; m < 4; m++)                                               \
      _Pragma("unroll")                                                       \
      for (int ks = 0; ks < 2; ks++) {                                        \
        int r_ = wr*64 + m*16 + l15;                                          \
        a[m][ks] = *(const short8*)&smA[(r_*64 + ks*32 + l4*8) ^ xorv];       \
      }                                                                       \
  } while (0)
#define RD_B(DST, NH) do {                                                    \
    _Pragma("unroll")                                                         \
    for (int n = 0; n < 2; n++)                                               \
      _Pragma("unroll")                                                       \
      for (int ks = 0; ks < 2; ks++) {                                        \
        int r_ = wc*64 + (NH)*32 + n*16 + l15;                                \
        DST[n][ks] = *(const short8*)&smB[(r_*64 + ks*32 + l4*8) ^ xorv];     \
      }                                                                       \
  } while (0)
#define MFMA16(NH, BB) do {                                                   \
    _Pragma("unroll")                                                         \
    for (int m = 0; m < 4; m++)                                               \
      _Pragma("unroll")                                                       \
      for (int n = 0; n < 2; n++)                                             \
        _Pragma("unroll")                                                     \
        for (int ks = 0; ks < 2; ks++)                                        \
          acc[m][(NH)*2+n] = __builtin_amdgcn_mfma_f32_16x16x32_bf16(         \
              a[m][ks], BB[n][ks], acc[m][(NH)*2+n], 0, 0, 0);                \
  } while (0)
#define BAR __builtin_amdgcn_s_barrier()

  int NT = K >> 6;
  STAGE_A(0, 0);
  STAGE_B(0, 0);
  STAGE_A(1, 1);
  STAGE_B(1, 1);
  asm volatile("s_waitcnt vmcnt(8)" ::: "memory");
  BAR;

  for (int t = 0; t < NT; ++t) {
    int buf = t & 1;
    const u16* smA = sm + buf * 16384;
    const u16* smB = smA + 8192;
    RD_A();
    RD_B(b0, 0);
    RD_B(b1, 1);
    asm volatile("s_waitcnt lgkmcnt(0)" ::: "memory");
    BAR;
    if (t + 2 < NT) {
      STAGE_A(t + 2, buf);
      STAGE_B(t + 2, buf);
    }
    __builtin_amdgcn_s_setprio(1);
    MFMA16(0, b0);
    MFMA16(1, b1);
    __builtin_amdgcn_s_setprio(0);
    if (t + 2 < NT) {
      asm volatile("s_waitcnt vmcnt(8)" ::: "memory");
    } else if (t + 1 < NT) {
      asm volatile("s_waitcnt vmcnt(0)" ::: "memory");
    }
    BAR;
  }
#undef STAGE_A
#undef STAGE_B
#undef RD_A
#undef RD_B
#undef MFMA16
#undef BAR

  #pragma unroll
  for (int in = 0; in < 4; in++) {
    int c = ncol0 + wc * 64 + in * 16 + l15;
    float bv = bias[(size_t)e * N + c];
    #pragma unroll
    for (int im = 0; im < 4; im++) {
      int rb = row0 + wr * 64 + im * 16 + l4 * 4;
      #pragma unroll
      for (int j = 0; j < 4; j++) {
        float v = acc[im][in][j] + bv;
        if (relu) v = fmaxf(v, 0.f);
        Out[(size_t)(rb + j) * N + c] = f2bf(v);
      }
    }
  }
}

// ---------------- GEMM1 (indirect A via tokmap) FIRST; transpose(W2) drains into slack ----------------
__global__ __launch_bounds__(256, 2) void gemm1tr_k(
    const u16* __restrict__ Xbf, const u16* __restrict__ Bt,
    const float* __restrict__ bias, u16* __restrict__ Out,
    const int* __restrict__ aoffs, const int* __restrict__ tokmap,
    const float* __restrict__ w2, u16* __restrict__ W2t)
{
  extern __shared__ u16 sm[];
  int id = blockIdx.x;
  if (id < G1BLKS) {
    int per = G1BLKS >> 3;
    int sid = (id & 7) * per + (id >> 3);           // XCD-chunked swizzle (2176 % 8 == 0)
    gemm128_body<true>(sm, Xbf, tokmap, Bt, bias, Out, aoffs, DIN, DHID, 1,
                       sid % 16, sid / 16);
    return;
  }
  int id2 = id - G1BLKS;
  int e = id2 / 640, r = id2 % 640;
  int rb = (r / 20) * 64, cb = (r % 20) * 64;       // W2: [2048, 1280]
  tr_tile(sm, w2 + (size_t)e * DHID * DIN, W2t + (size_t)e * DHID * DIN,
          DHID, DIN, rb, cb);
}

// ---------------- GEMM2: plain 128x128 ----------------
__global__ __launch_bounds__(256, 2) void gemm128_k(
    const u16* __restrict__ A, const u16* __restrict__ Bt,
    const float* __restrict__ bias, u16* __restrict__ Out,
    const int* __restrict__ aoffs, int K, int N, int relu)
{
  extern __shared__ u16 sm[];
  int nwgx = gridDim.x;
  int id = blockIdx.y * nwgx + blockIdx.x;
  int per = (nwgx * gridDim.y) >> 3;
  int sid = (id & 7) * per + (id >> 3);
  gemm128_body<false>(sm, A, nullptr, Bt, bias, Out, aoffs, K, N, relu,
                      sid % nwgx, sid / nwgx);
}

// ---------------- ln v2: one wave per token, vectorized, shuffle-only reduce ----------------
__global__ __launch_bounds__(256) void ln_k(
    const float* __restrict__ x, const u16* __restrict__ Y,
    const int* __restrict__ rowmap, const int* __restrict__ topk_e,
    const float* __restrict__ topk_g, const float* __restrict__ gamma,
    const float* __restrict__ beta, float* __restrict__ out)
{
  int w = threadIdx.x >> 6, lane = threadIdx.x & 63;
  int t = blockIdx.x * 4 + w;
  int r0 = rowmap[2*t], r1 = rowmap[2*t+1];
  int e0 = topk_e[2*t], e1 = topk_e[2*t+1];
  float g0 = topk_g[2*t], g1 = topk_g[2*t+1];
  const float4v* xt = (const float4v*)(x + (size_t)t * DIN);
  const us4* y0p = (const us4*)(Y + (size_t)r0 * DIN);
  const us4* y1p = (const us4*)(Y + (size_t)r1 * DIN);
  float4v v0[5], v1[5];
  float s0 = 0.f, q0 = 0.f, s1 = 0.f, q1 = 0.f;
  #pragma unroll
  for (int i = 0; i < 5; i++) {
    int q = i * 64 + lane;
    float4v xv = xt[q];
    us4 ya = y0p[q], yb = y1p[q];
    #pragma unroll
    for (int j = 0; j < 4; j++) {
      float aa = xv[j] + bf2f(ya[j]);
      float bb = xv[j] + bf2f(yb[j]);
      v0[i][j] = aa; v1[i][j] = bb;
      s0 += aa; q0 += aa * aa; s1 += bb; q1 += bb * bb;
    }
  }
  #pragma unroll
  for (int off = 32; off; off >>= 1) {
    s0 += __shfl_xor(s0, off); q0 += __shfl_xor(q0, off);
    s1 += __shfl_xor(s1, off); q1 += __shfl_xor(q1, off);
  }
  const float inv = 1.f / DIN;
  float mu0 = s0 * inv, mu1 = s1 * inv;
  float rs0 = rsqrtf(fmaxf(q0 * inv - mu0 * mu0, 0.f) + 1e-6f);
  float rs1 = rsqrtf(fmaxf(q1 * inv - mu1 * mu1, 0.f) + 1e-6f);
  const float4v* ga0 = (const float4v*)(gamma + (size_t)e0 * DIN);
  const float4v* be0 = (const float4v*)(beta  + (size_t)e0 * DIN);
  const float4v* ga1 = (const float4v*)(gamma + (size_t)e1 * DIN);
  const float4v* be1 = (const float4v*)(beta  + (size_t)e1 * DIN);
  float4v* op = (float4v*)(out + (size_t)t * DIN);
  #pragma unroll
  for (int i = 0; i < 5; i++) {
    int q = i * 64 + lane;
    float4v gA = ga0[q], bA = be0[q], gB = ga1[q], bB = be1[q];
    float4v o;
    #pragma unroll
    for (int j = 0; j < 4; j++) {
      float n0 = (v0[i][j] - mu0) * rs0 * gA[j] + bA[j];
      float n1 = (v1[i][j] - mu1) * rs1 * gB[j] + bB[j];
      o[j] = g0 * n0 + g1 * n1;
    }
    op[q] = o;
  }
}

extern "C" void kernel_launch(void* const* d_in, const int* in_sizes, int n_in,
                              void* d_out, int out_size, void* d_ws, size_t ws_size,
                              hipStream_t stream)
{
  const float* x     = (const float*)d_in[0];
  const float* noise = (const float*)d_in[1];
  const float* wr    = (const float*)d_in[2];
  const float* br    = (const float*)d_in[3];
  const float* wn    = (const float*)d_in[4];
  const float* bn    = (const float*)d_in[5];
  const float* w1    = (const float*)d_in[6];
  const float* b1    = (const float*)d_in[7];
  const float* w2    = (const float*)d_in[8];
  const float* b2    = (const float*)d_in[9];
  const float* gamma = (const float*)d_in[10];
  const float* beta  = (const float*)d_in[11];
  float* out = (float*)d_out;
  char* ws = (char*)d_ws;

  int*   aoffs   = (int*)(ws + 128);
  int*   rowmap  = (int*)(ws + 4096);
  int*   topk_e  = (int*)(ws + 4096 + 65536);
  float* topk_g  = (float*)(ws + 4096 + 2 * 65536);
  int*   tokmap  = (int*)(ws + 4096 + 3 * 65536);   // RCAP ints = 68 KB

  const size_t XB_OFF   = (size_t)1 << 20;
  const size_t XB_BYTES = (size_t)TOK * DIN * 2;    // 21.0 MB
  const size_t H_BYTES  = (size_t)RCAP * DHID * 2;  // 71.3 MB
  const size_t Y_BYTES  = (size_t)RCAP * DIN * 2;   // 44.6 MB
  const size_t WT_BYTES = (size_t)NEXP * DHID * DIN * 2; // 41.9 MB each
  u16* Xbf = (u16*)(ws + XB_OFF);
  u16* Hb  = (u16*)(ws + XB_OFF + XB_BYTES);
  u16* Yb  = (u16*)(ws + XB_OFF + XB_BYTES + H_BYTES);
  u16* W1t = (u16*)(ws + XB_OFF + XB_BYTES + H_BYTES + Y_BYTES);
  u16* W2t = (u16*)(ws + XB_OFF + XB_BYTES + H_BYTES + Y_BYTES + WT_BYTES);

  routertr_k<<<RTRBLK + XBBLK + TRBLK1, 256, 0, stream>>>(
      w1, W1t, x, noise, wr, br, wn, bn, topk_e, topk_g, Xbf);
  scan_k<<<1, 1024, 0, stream>>>(topk_e, rowmap, tokmap, aoffs);
  gemm1tr_k<<<G1BLKS + TRBLK2, 256, 65536, stream>>>(Xbf, W1t, b1, Hb, aoffs, tokmap, w2, W2t);
  gemm128_k<<<dim3(DIN/128, MT128), 256, 65536, stream>>>(Hb, W2t, b2, Yb, aoffs, DHID, DIN, 0);
  ln_k<<<TOK/4, 256, 0, stream>>>(x, Yb, rowmap, topk_e, topk_g, gamma, beta, out);
}